// Round 8
// baseline (367.134 us; speedup 1.0000x reference)
//
#include <hip/hip_runtime.h>
#include <hip/hip_bf16.h>
#include <cstdint>
#include <cstddef>

#define NN 10000
#define MAXDEG 128
#define LDX 384

#define PA_BLKS 2048
#define PA_STEPS 48
#define PA_REG (PA_STEPS * 256)     // 12288 float4 per block
#define ZERO_BLKS 40
#define PA_GRID (PA_BLKS + ZERO_BLKS + 1)

#define GEMM_BLKS 313
#define PB_GRID (GEMM_BLKS + PA_BLKS)

typedef __attribute__((ext_vector_type(8))) short bf16x8;
typedef __attribute__((ext_vector_type(4))) float f32x4;

__device__ __forceinline__ float bf2f(unsigned short u) {
    union { unsigned int i; float f; } c; c.i = ((unsigned int)u) << 16; return c.f;
}
__device__ __forceinline__ unsigned short f2bf(float f) {
    union { float f; unsigned int i; } c; c.f = f;
    unsigned int x = c.i;
    return (unsigned short)((x + 0x7fffu + ((x >> 16) & 1u)) >> 16);
}

// ---------- DIAGNOSTIC: pure streaming read, 2 passes over 400 MB ----------
// Exact same shape as scan_detect (2048 blocks, 48 steps, ring-8, clamped
// addresses) but ZERO detect logic: just OR-reduce. Store is data-dependent
// and effectively never taken (keeps the loads alive).
__global__ __launch_bounds__(256) void rd_bench(const uint4* __restrict__ src,
                                                int total4,
                                                unsigned int* __restrict__ dummy) {
    int b = blockIdx.x, t = threadIdx.x;
    int LIM = total4 - 1;
    unsigned acc = 0u;
    for (int pass = 0; pass < 2; ++pass) {
        int p0 = b * PA_REG + t;
        uint4 buf[8];
        #pragma unroll
        for (int d = 0; d < 8; ++d) buf[d] = src[min(p0 + d * 256, LIM)];
        #pragma unroll
        for (int s = 0; s < PA_STEPS; ++s) {
            uint4 u = buf[s & 7];
            buf[s & 7] = src[min(p0 + (s + 8) * 256, LIM)];
            acc |= (u.x | u.y) | (u.z | u.w);
        }
    }
    if (acc == 0x5A5A5A5Au) dummy[b * 256 + t] = acc;
}

// ---------- Pass A: store-free detector (+ cnt zero + weight convert) -------
__global__ __launch_bounds__(256) void scan_detect(
        const uint4* __restrict__ adj4, int total4,
        unsigned int* __restrict__ bm, int* __restrict__ cnt,
        const float* __restrict__ W_cheb, const float* __restrict__ W_out,
        unsigned short* __restrict__ Wtc, unsigned short* __restrict__ Wto) {
    int b = blockIdx.x;
    int t = threadIdx.x;

    if (b >= PA_BLKS) {
        int xb = b - PA_BLKS;
        if (xb < ZERO_BLKS) {
            int i = xb * 256 + t;
            if (i < NN) cnt[i] = 0;
        } else {
            for (int idx = t; idx < 384 * 128; idx += 256) {
                int k = idx >> 7, c = idx & 127;
                Wtc[c * 384 + k] = f2bf(W_cheb[idx]);
            }
            for (int idx = t; idx < 128 * 64; idx += 256) {
                int k = idx >> 6, c = idx & 63;
                Wto[c * 128 + k] = f2bf(W_out[idx]);
            }
        }
        return;
    }

    int p0 = b * PA_REG + t;
    int LIM = total4 - 1;

    uint4 buf[4];
    #pragma unroll
    for (int d = 0; d < 4; ++d)
        buf[d] = adj4[min(p0 + d * 256, LIM)];

    unsigned acc[6] = {0u, 0u, 0u, 0u, 0u, 0u};

    #pragma unroll
    for (int s = 0; s < PA_STEPS; ++s) {
        uint4 u = buf[s & 3];
        buf[s & 3] = adj4[min(p0 + (s + 4) * 256, LIM)];   // prefetch, clamped
        int p = p0 + s * 256;
        unsigned nib = (u.x != 0u ? 1u : 0u) | (u.y != 0u ? 2u : 0u)
                     | (u.z != 0u ? 4u : 0u) | (u.w != 0u ? 8u : 0u);
        if (p > LIM) nib = 0u;
        acc[s >> 3] |= nib << ((s & 7) * 4);
    }

    #pragma unroll
    for (int r = 0; r < 6; ++r)
        bm[(b * 6 + r) * 256 + t] = acc[r];
}

// ---------- Pass B: bitmap decode -> cnt/csr atomics | fused gemm_in --------
__global__ __launch_bounds__(256) void decode_gemm(
        const unsigned int* __restrict__ bm,
        int* __restrict__ cnt, int* __restrict__ csr,
        const float* __restrict__ x, const float* __restrict__ W_in,
        const float* __restrict__ b_in, unsigned short* __restrict__ Xc) {
    __shared__ float smem[5120];   // 20 KB (gemm branch only)
    int b = blockIdx.x;
    int t = threadIdx.x;

    if (b < GEMM_BLKS) {
        // ---- gemm_in: X0 = relu(x @ W_in + b_in) -> bf16 Xc[:,0:128] ----
        constexpr int K = 256, N = 128, BM = 32, KC = 32;
        float* Wl = smem;
        float* Al = smem + KC * N;
        int r0 = b * BM;
        int c2 = t & 63;
        int g  = t >> 6;
        float2 acc[8];
        #pragma unroll
        for (int i = 0; i < 8; ++i) acc[i] = make_float2(0.f, 0.f);

        for (int kk = 0; kk < K; kk += KC) {
            __syncthreads();
            #pragma unroll
            for (int i = 0; i < KC * N / 4 / 256; ++i) {
                int idx = t + i * 256;
                ((float4*)Wl)[idx] = ((const float4*)(W_in + (size_t)kk * N))[idx];
            }
            {
                int row = t >> 3;
                int cf  = t & 7;
                float4 v = make_float4(0.f, 0.f, 0.f, 0.f);
                if (r0 + row < NN)
                    v = *(const float4*)(x + (size_t)(r0 + row) * K + kk + cf * 4);
                *(float4*)(Al + row * KC + cf * 4) = v;
            }
            __syncthreads();
            for (int k = 0; k < KC; k += 4) {
                float4 av[8];
                #pragma unroll
                for (int rr = 0; rr < 8; ++rr)
                    av[rr] = *(const float4*)(Al + (g * 8 + rr) * KC + k);
                #pragma unroll
                for (int k2 = 0; k2 < 4; ++k2) {
                    float2 wv = *(const float2*)(Wl + (k + k2) * N + c2 * 2);
                    #pragma unroll
                    for (int rr = 0; rr < 8; ++rr) {
                        float a = (k2 == 0) ? av[rr].x : (k2 == 1) ? av[rr].y
                                  : (k2 == 2) ? av[rr].z : av[rr].w;
                        acc[rr].x = fmaf(a, wv.x, acc[rr].x);
                        acc[rr].y = fmaf(a, wv.y, acc[rr].y);
                    }
                }
            }
        }
        float2 bv = *(const float2*)(b_in + c2 * 2);
        #pragma unroll
        for (int rr = 0; rr < 8; ++rr) {
            int r = r0 + g * 8 + rr;
            if (r < NN) {
                float vx = fmaxf(acc[rr].x + bv.x, 0.f);
                float vy = fmaxf(acc[rr].y + bv.y, 0.f);
                uint32_t o = (uint32_t)f2bf(vx) | ((uint32_t)f2bf(vy) << 16);
                *(uint32_t*)(Xc + (size_t)r * LDX + c2 * 2) = o;
            }
        }
    } else {
        int sb = b - GEMM_BLKS;   // 0..PA_BLKS-1
        #pragma unroll
        for (int r = 0; r < 6; ++r) {
            unsigned w = bm[(sb * 6 + r) * 256 + t];
            while (w) {
                int bit = __ffs(w) - 1;
                w &= w - 1u;
                int s = r * 8 + (bit >> 2);
                int c = bit & 3;
                int p = sb * PA_REG + s * 256 + t;
                int l = p * 4 + c;           // < 1e8, fits int32
                int i = l / NN;              // row (src)
                int j = l - i * NN;          // col (dst)
                int pos = atomicAdd(&cnt[j], 1);
                if (pos < MAXDEG) csr[j * MAXDEG + pos] = i;
            }
        }
    }
}

// ---------------- sparse propagation (bf16, unroll-4, indep chains) ---------
template<bool SUB>
__global__ __launch_bounds__(256) void prop_k(unsigned short* __restrict__ X,
                                              const int* __restrict__ csr,
                                              const int* __restrict__ cnt,
                                              int srcOff, int dstOff, float scale) {
    int j = blockIdx.x * 4 + (threadIdx.x >> 6);
    if (j >= NN) return;
    int lane = threadIdx.x & 63;
    int cj = cnt[j];
    int cn = min(cj, MAXDEG);
    const int* nb = csr + j * MAXDEG;
    float ax0 = 0.f, ay0 = 0.f, ax1 = 0.f, ay1 = 0.f;
    float ax2 = 0.f, ay2 = 0.f, ax3 = 0.f, ay3 = 0.f;
    int e = 0;
    for (; e + 4 <= cn; e += 4) {
        int i0 = nb[e], i1 = nb[e + 1], i2 = nb[e + 2], i3 = nb[e + 3];
        int c0 = cnt[i0], c1 = cnt[i1], c2 = cnt[i2], c3 = cnt[i3];
        uint32_t h0 = *(const uint32_t*)(X + (size_t)i0 * LDX + srcOff + lane * 2);
        uint32_t h1 = *(const uint32_t*)(X + (size_t)i1 * LDX + srcOff + lane * 2);
        uint32_t h2 = *(const uint32_t*)(X + (size_t)i2 * LDX + srcOff + lane * 2);
        uint32_t h3 = *(const uint32_t*)(X + (size_t)i3 * LDX + srcOff + lane * 2);
        float w0 = rsqrtf(fmaxf((float)c0, 1.f));
        float w1 = rsqrtf(fmaxf((float)c1, 1.f));
        float w2 = rsqrtf(fmaxf((float)c2, 1.f));
        float w3 = rsqrtf(fmaxf((float)c3, 1.f));
        ax0 = fmaf(w0, bf2f((unsigned short)h0), ax0);
        ay0 = fmaf(w0, bf2f((unsigned short)(h0 >> 16)), ay0);
        ax1 = fmaf(w1, bf2f((unsigned short)h1), ax1);
        ay1 = fmaf(w1, bf2f((unsigned short)(h1 >> 16)), ay1);
        ax2 = fmaf(w2, bf2f((unsigned short)h2), ax2);
        ay2 = fmaf(w2, bf2f((unsigned short)(h2 >> 16)), ay2);
        ax3 = fmaf(w3, bf2f((unsigned short)h3), ax3);
        ay3 = fmaf(w3, bf2f((unsigned short)(h3 >> 16)), ay3);
    }
    for (; e < cn; ++e) {
        int i0 = nb[e];
        float w0 = rsqrtf(fmaxf((float)cnt[i0], 1.f));
        uint32_t h0 = *(const uint32_t*)(X + (size_t)i0 * LDX + srcOff + lane * 2);
        ax0 = fmaf(w0, bf2f((unsigned short)h0), ax0);
        ay0 = fmaf(w0, bf2f((unsigned short)(h0 >> 16)), ay0);
    }
    float s = scale * rsqrtf(fmaxf((float)cj, 1.f));
    float rx = s * ((ax0 + ax1) + (ax2 + ax3));
    float ry = s * ((ay0 + ay1) + (ay2 + ay3));
    if (SUB) {
        uint32_t x0 = *(const uint32_t*)(X + (size_t)j * LDX + lane * 2);
        rx -= bf2f((unsigned short)x0);
        ry -= bf2f((unsigned short)(x0 >> 16));
    }
    uint32_t o = (uint32_t)f2bf(rx) | ((uint32_t)f2bf(ry) << 16);
    *(uint32_t*)(X + (size_t)j * LDX + dstOff + lane * 2) = o;
}

// -------- MFMA fused: hc = relu(Xc@Wc + bc); out = hc@Wo + bo ---------------
__global__ __launch_bounds__(256) void cheb_out_mfma(
        const unsigned short* __restrict__ Xc,   // [NN][384] bf16
        const unsigned short* __restrict__ Wtc,  // [128][384] bf16 (W_cheb^T)
        const float* __restrict__ bc,
        const unsigned short* __restrict__ Wto,  // [64][128] bf16 (W_out^T)
        const float* __restrict__ bo,
        float* __restrict__ out) {
    __shared__ unsigned short hcL[32][136];
    int t = threadIdx.x;
    int w = t >> 6, lane = t & 63;
    int r0 = blockIdx.x * 32;
    int lr = lane & 15;
    int kg = lane >> 4;

    f32x4 acc[2][2] = {};
    for (int k0 = 0; k0 < 384; k0 += 32) {
        bf16x8 a[2], b[2];
        #pragma unroll
        for (int m = 0; m < 2; ++m) {
            int row = r0 + m * 16 + lr;
            row = min(row, NN - 1);
            a[m] = *(const bf16x8*)(Xc + (size_t)row * LDX + k0 + kg * 8);
        }
        #pragma unroll
        for (int n = 0; n < 2; ++n) {
            int col = w * 32 + n * 16 + lr;
            b[n] = *(const bf16x8*)(Wtc + (size_t)col * 384 + k0 + kg * 8);
        }
        #pragma unroll
        for (int m = 0; m < 2; ++m)
            #pragma unroll
            for (int n = 0; n < 2; ++n)
                acc[m][n] = __builtin_amdgcn_mfma_f32_16x16x32_bf16(a[m], b[n], acc[m][n], 0, 0, 0);
    }
    #pragma unroll
    for (int m = 0; m < 2; ++m) {
        #pragma unroll
        for (int n = 0; n < 2; ++n) {
            int col = w * 32 + n * 16 + lr;
            float bv = bc[col];
            #pragma unroll
            for (int r = 0; r < 4; ++r) {
                int row = m * 16 + kg * 4 + r;
                hcL[row][col] = f2bf(fmaxf(acc[m][n][r] + bv, 0.f));
            }
        }
    }
    __syncthreads();
    int rt = w >> 1, ch = w & 1;
    f32x4 a2[2] = {};
    for (int k0 = 0; k0 < 128; k0 += 32) {
        bf16x8 af = *(const bf16x8*)(&hcL[rt * 16 + lr][k0 + kg * 8]);
        #pragma unroll
        for (int n = 0; n < 2; ++n) {
            int col = ch * 32 + n * 16 + lr;
            bf16x8 bf_ = *(const bf16x8*)(Wto + (size_t)col * 128 + k0 + kg * 8);
            a2[n] = __builtin_amdgcn_mfma_f32_16x16x32_bf16(af, bf_, a2[n], 0, 0, 0);
        }
    }
    #pragma unroll
    for (int n = 0; n < 2; ++n) {
        int col = ch * 32 + n * 16 + lr;
        float bv = bo[col];
        #pragma unroll
        for (int r = 0; r < 4; ++r) {
            int row = r0 + rt * 16 + kg * 4 + r;
            if (row < NN) out[(size_t)row * 64 + col] = a2[n][r] + bv;
        }
    }
}

extern "C" void kernel_launch(void* const* d_in, const int* in_sizes, int n_in,
                              void* d_out, int out_size, void* d_ws, size_t ws_size,
                              hipStream_t stream) {
    const float* x      = (const float*)d_in[0];
    const float* adj    = (const float*)d_in[1];
    const float* W_in   = (const float*)d_in[2];
    const float* b_in   = (const float*)d_in[3];
    const float* W_cheb = (const float*)d_in[4];
    const float* b_cheb = (const float*)d_in[5];
    const float* W_out  = (const float*)d_in[6];
    const float* b_out  = (const float*)d_in[7];
    float* out = (float*)d_out;

    char* ws = (char*)d_ws;
    int*            cnt = (int*)(ws + 0);                     // 40,000 B
    int*            csr = (int*)(ws + 40960);                 // 5.12 MB
    unsigned int*   bm  = (unsigned int*)(ws + 5160960);      // 12.58 MB bitmap
    unsigned short* Xc  = (unsigned short*)(ws + 17743872);   // 7.68 MB
    unsigned short* Wtc = (unsigned short*)(ws + 25427968);   // 98,304 B
    unsigned short* Wto = (unsigned short*)(ws + 25526272);   // 16,384 B
    unsigned int* dummy = (unsigned int*)(ws + 25600000);     // 2 MB diag sink

    int adj_total = in_sizes[1];   // 100,000,000

    scan_detect<<<PA_GRID, 256, 0, stream>>>(
        (const uint4*)adj, adj_total / 4, bm, cnt, W_cheb, W_out, Wtc, Wto);
    decode_gemm<<<PB_GRID, 256, 0, stream>>>(bm, cnt, csr, x, W_in, b_in, Xc);
    prop_k<false><<<(NN + 3) / 4, 256, 0, stream>>>(Xc, csr, cnt, 0, 128, -1.0f);
    prop_k<true><<<(NN + 3) / 4, 256, 0, stream>>>(Xc, csr, cnt, 128, 256, -2.0f);
    cheb_out_mfma<<<(NN + 31) / 32, 256, 0, stream>>>(Xc, Wtc, b_cheb, Wto, b_out, out);

    // ---- DIAGNOSTICS (do not affect outputs) ----
    // rd over the adj input allocation (2x400 MB)
    rd_bench<<<PA_BLKS, 256, 0, stream>>>((const uint4*)adj, adj_total / 4, dummy);
    // rd over a far workspace region (2x400 MB), only if ws is big enough
    if (ws_size >= 1000u * 1000u * 1000u) {
        const uint4* wsrc = (const uint4*)(ws + 512u * 1024u * 1024u);
        rd_bench<<<PA_BLKS, 256, 0, stream>>>(wsrc, 25000000, dummy);
    }
}

// Round 9
// 234.505 us; speedup vs baseline: 1.5656x; 1.5656x over previous
//
#include <hip/hip_runtime.h>
#include <hip/hip_bf16.h>
#include <cstdint>
#include <cstddef>

#define NN 10000
#define MAXDEG 128
#define LDX 384

#define COLSCAN_BLKS 1250          // 125 row-blocks x 10 col-stripes
#define RB_ROWS 80
#define NRB 125
#define SEG2 12                    // slots per (col, row-block); P(overflow) ~ 0
#define GEMM_BLKS 313
#define FATG (COLSCAN_BLKS + GEMM_BLKS + 1)

typedef __attribute__((ext_vector_type(8))) short bf16x8;
typedef __attribute__((ext_vector_type(4))) float f32x4;

__device__ __forceinline__ float bf2f(unsigned short u) {
    union { unsigned int i; float f; } c; c.i = ((unsigned int)u) << 16; return c.f;
}
__device__ __forceinline__ unsigned short f2bf(float f) {
    union { float f; unsigned int i; } c; c.f = f;
    unsigned int x = c.i;
    return (unsigned short)((x + 0x7fffu + ((x >> 16) & 1u)) >> 16);
}

// ---- fat kernel: column-owned scan (0..1249) | gemm_in | weight convert ----
__global__ __launch_bounds__(256) void fat_colscan_gemm(
        const float* __restrict__ A,          // [NN][NN] row-major
        int* __restrict__ csr2,               // [NRB][NN][SEG2]
        int* __restrict__ cnt2,               // [NN][128]
        const float* __restrict__ x, const float* __restrict__ W_in,
        const float* __restrict__ b_in,
        const float* __restrict__ W_cheb, const float* __restrict__ W_out,
        unsigned short* __restrict__ Xc,
        unsigned short* __restrict__ Wtc, unsigned short* __restrict__ Wto) {
    __shared__ float smem[5120];   // 20 KB (gemm branch only)
    int bid = blockIdx.x;
    int t = threadIdx.x;

    if (bid < COLSCAN_BLKS) {
        // ---- column-owned scan: thread owns 4 adjacent columns ----
        if (t >= 250) return;
        int rb  = bid / 10;              // 0..124
        int cbs = bid % 10;              // col stripe of 1000
        int r0  = rb * RB_ROWS;
        int c   = cbs * 1000 + t * 4;    // 4 columns c..c+3
        const float4* base = (const float4*)A;
        int idx0 = r0 * (NN / 4) + (c >> 2);

        float4 buf[8];
        #pragma unroll
        for (int d = 0; d < 8; ++d)
            buf[d] = base[idx0 + d * (NN / 4)];

        int n0 = 0, n1 = 0, n2 = 0, n3 = 0;
        size_t segbase = ((size_t)rb * NN + c) * SEG2;

        #pragma unroll 8
        for (int r = 0; r < RB_ROWS; ++r) {
            float4 v = buf[r & 7];
            buf[r & 7] = base[idx0 + min(r + 8, RB_ROWS - 1) * (NN / 4)];
            int row = r0 + r;
            if (v.x != 0.f) { if (n0 < SEG2) csr2[segbase + n0] = row; n0++; }
            if (v.y != 0.f) { if (n1 < SEG2) csr2[segbase + SEG2 + n1] = row; n1++; }
            if (v.z != 0.f) { if (n2 < SEG2) csr2[segbase + 2 * SEG2 + n2] = row; n2++; }
            if (v.w != 0.f) { if (n3 < SEG2) csr2[segbase + 3 * SEG2 + n3] = row; n3++; }
        }
        cnt2[(c + 0) * 128 + rb] = n0;
        cnt2[(c + 1) * 128 + rb] = n1;
        cnt2[(c + 2) * 128 + rb] = n2;
        cnt2[(c + 3) * 128 + rb] = n3;
    } else if (bid < COLSCAN_BLKS + GEMM_BLKS) {
        // ---- gemm_in: X0 = relu(x @ W_in + b_in) -> bf16 Xc[:,0:128] ----
        constexpr int K = 256, N = 128, BM = 32, KC = 32;
        float* Wl = smem;
        float* Al = smem + KC * N;
        int r0 = (bid - COLSCAN_BLKS) * BM;
        int c2 = t & 63;
        int g  = t >> 6;
        float2 acc[8];
        #pragma unroll
        for (int i = 0; i < 8; ++i) acc[i] = make_float2(0.f, 0.f);

        for (int kk = 0; kk < K; kk += KC) {
            __syncthreads();
            #pragma unroll
            for (int i = 0; i < KC * N / 4 / 256; ++i) {
                int idx = t + i * 256;
                ((float4*)Wl)[idx] = ((const float4*)(W_in + (size_t)kk * N))[idx];
            }
            {
                int row = t >> 3;
                int cf  = t & 7;
                float4 v = make_float4(0.f, 0.f, 0.f, 0.f);
                if (r0 + row < NN)
                    v = *(const float4*)(x + (size_t)(r0 + row) * K + kk + cf * 4);
                *(float4*)(Al + row * KC + cf * 4) = v;
            }
            __syncthreads();
            for (int k = 0; k < KC; k += 4) {
                float4 av[8];
                #pragma unroll
                for (int rr = 0; rr < 8; ++rr)
                    av[rr] = *(const float4*)(Al + (g * 8 + rr) * KC + k);
                #pragma unroll
                for (int k2 = 0; k2 < 4; ++k2) {
                    float2 wv = *(const float2*)(Wl + (k + k2) * N + c2 * 2);
                    #pragma unroll
                    for (int rr = 0; rr < 8; ++rr) {
                        float a = (k2 == 0) ? av[rr].x : (k2 == 1) ? av[rr].y
                                  : (k2 == 2) ? av[rr].z : av[rr].w;
                        acc[rr].x = fmaf(a, wv.x, acc[rr].x);
                        acc[rr].y = fmaf(a, wv.y, acc[rr].y);
                    }
                }
            }
        }
        float2 bv = *(const float2*)(b_in + c2 * 2);
        #pragma unroll
        for (int rr = 0; rr < 8; ++rr) {
            int r = r0 + g * 8 + rr;
            if (r < NN) {
                float vx = fmaxf(acc[rr].x + bv.x, 0.f);
                float vy = fmaxf(acc[rr].y + bv.y, 0.f);
                uint32_t o = (uint32_t)f2bf(vx) | ((uint32_t)f2bf(vy) << 16);
                *(uint32_t*)(Xc + (size_t)r * LDX + c2 * 2) = o;
            }
        }
    } else {
        // ---- one-time weight transpose+convert ----
        for (int idx = t; idx < 384 * 128; idx += 256) {
            int k = idx >> 7, c = idx & 127;
            Wtc[c * 384 + k] = f2bf(W_cheb[idx]);
        }
        for (int idx = t; idx < 128 * 64; idx += 256) {
            int k = idx >> 6, c = idx & 63;
            Wto[c * 128 + k] = f2bf(W_out[idx]);
        }
    }
}

// ---- stitch: concat per-rowblock segments -> csr, compute cnt & norm -------
// wave per column; lanes l and l+64 handle row-blocks l and l+64.
__global__ __launch_bounds__(256) void stitch_norm(
        const int* __restrict__ csr2, const int* __restrict__ cnt2,
        int* __restrict__ csr, int* __restrict__ cnt, float* __restrict__ nrm) {
    int w = threadIdx.x >> 6, l = threadIdx.x & 63;
    int c = blockIdx.x * 4 + w;
    if (c >= NN) return;

    int a  = (l < NRB)      ? cnt2[c * 128 + l]      : 0;
    int bb = (l + 64 < NRB) ? cnt2[c * 128 + 64 + l] : 0;

    int xa = a, xb = bb;
    #pragma unroll
    for (int d = 1; d < 64; d <<= 1) {
        int ya = __shfl_up(xa, d);
        int yb = __shfl_up(xb, d);
        if (l >= d) { xa += ya; xb += yb; }
    }
    int totalA = __shfl(xa, 63);
    int total  = totalA + __shfl(xb, 63);
    int offA = xa - a;
    int offB = totalA + xb - bb;

    const int* segA = csr2 + ((size_t)l * NN + c) * SEG2;
    for (int e = 0; e < a; ++e) {
        int o = offA + e;
        if (o < MAXDEG) csr[(size_t)c * MAXDEG + o] = segA[e];
    }
    if (l + 64 < NRB) {
        const int* segB = csr2 + ((size_t)(l + 64) * NN + c) * SEG2;
        for (int e = 0; e < bb; ++e) {
            int o = offB + e;
            if (o < MAXDEG) csr[(size_t)c * MAXDEG + o] = segB[e];
        }
    }
    if (l == 0) {
        cnt[c] = min(total, MAXDEG);
        nrm[c] = rsqrtf(fmaxf((float)total, 1.f));
    }
}

// ---------------- sparse propagation (bf16, unroll-4, norm array) -----------
template<bool SUB>
__global__ __launch_bounds__(256) void prop_k(unsigned short* __restrict__ X,
                                              const int* __restrict__ csr,
                                              const int* __restrict__ cnt,
                                              const float* __restrict__ nrm,
                                              int srcOff, int dstOff, float scale) {
    int j = blockIdx.x * 4 + (threadIdx.x >> 6);
    if (j >= NN) return;
    int lane = threadIdx.x & 63;
    int cn = cnt[j];
    const int* nb = csr + (size_t)j * MAXDEG;
    float ax0 = 0.f, ay0 = 0.f, ax1 = 0.f, ay1 = 0.f;
    float ax2 = 0.f, ay2 = 0.f, ax3 = 0.f, ay3 = 0.f;
    int e = 0;
    for (; e + 4 <= cn; e += 4) {
        int i0 = nb[e], i1 = nb[e + 1], i2 = nb[e + 2], i3 = nb[e + 3];
        float w0 = nrm[i0], w1 = nrm[i1], w2 = nrm[i2], w3 = nrm[i3];
        uint32_t h0 = *(const uint32_t*)(X + (size_t)i0 * LDX + srcOff + lane * 2);
        uint32_t h1 = *(const uint32_t*)(X + (size_t)i1 * LDX + srcOff + lane * 2);
        uint32_t h2 = *(const uint32_t*)(X + (size_t)i2 * LDX + srcOff + lane * 2);
        uint32_t h3 = *(const uint32_t*)(X + (size_t)i3 * LDX + srcOff + lane * 2);
        ax0 = fmaf(w0, bf2f((unsigned short)h0), ax0);
        ay0 = fmaf(w0, bf2f((unsigned short)(h0 >> 16)), ay0);
        ax1 = fmaf(w1, bf2f((unsigned short)h1), ax1);
        ay1 = fmaf(w1, bf2f((unsigned short)(h1 >> 16)), ay1);
        ax2 = fmaf(w2, bf2f((unsigned short)h2), ax2);
        ay2 = fmaf(w2, bf2f((unsigned short)(h2 >> 16)), ay2);
        ax3 = fmaf(w3, bf2f((unsigned short)h3), ax3);
        ay3 = fmaf(w3, bf2f((unsigned short)(h3 >> 16)), ay3);
    }
    for (; e < cn; ++e) {
        int i0 = nb[e];
        float w0 = nrm[i0];
        uint32_t h0 = *(const uint32_t*)(X + (size_t)i0 * LDX + srcOff + lane * 2);
        ax0 = fmaf(w0, bf2f((unsigned short)h0), ax0);
        ay0 = fmaf(w0, bf2f((unsigned short)(h0 >> 16)), ay0);
    }
    float s = scale * nrm[j];
    float rx = s * ((ax0 + ax1) + (ax2 + ax3));
    float ry = s * ((ay0 + ay1) + (ay2 + ay3));
    if (SUB) {
        uint32_t x0 = *(const uint32_t*)(X + (size_t)j * LDX + lane * 2);
        rx -= bf2f((unsigned short)x0);
        ry -= bf2f((unsigned short)(x0 >> 16));
    }
    uint32_t o = (uint32_t)f2bf(rx) | ((uint32_t)f2bf(ry) << 16);
    *(uint32_t*)(X + (size_t)j * LDX + dstOff + lane * 2) = o;
}

// -------- MFMA fused: hc = relu(Xc@Wc + bc); out = hc@Wo + bo ---------------
__global__ __launch_bounds__(256) void cheb_out_mfma(
        const unsigned short* __restrict__ Xc,   // [NN][384] bf16
        const unsigned short* __restrict__ Wtc,  // [128][384] bf16 (W_cheb^T)
        const float* __restrict__ bc,
        const unsigned short* __restrict__ Wto,  // [64][128] bf16 (W_out^T)
        const float* __restrict__ bo,
        float* __restrict__ out) {
    __shared__ unsigned short hcL[32][136];
    int t = threadIdx.x;
    int w = t >> 6, lane = t & 63;
    int r0 = blockIdx.x * 32;
    int lr = lane & 15;
    int kg = lane >> 4;

    f32x4 acc[2][2] = {};
    for (int k0 = 0; k0 < 384; k0 += 32) {
        bf16x8 a[2], b[2];
        #pragma unroll
        for (int m = 0; m < 2; ++m) {
            int row = r0 + m * 16 + lr;
            row = min(row, NN - 1);
            a[m] = *(const bf16x8*)(Xc + (size_t)row * LDX + k0 + kg * 8);
        }
        #pragma unroll
        for (int n = 0; n < 2; ++n) {
            int col = w * 32 + n * 16 + lr;
            b[n] = *(const bf16x8*)(Wtc + (size_t)col * 384 + k0 + kg * 8);
        }
        #pragma unroll
        for (int m = 0; m < 2; ++m)
            #pragma unroll
            for (int n = 0; n < 2; ++n)
                acc[m][n] = __builtin_amdgcn_mfma_f32_16x16x32_bf16(a[m], b[n], acc[m][n], 0, 0, 0);
    }
    #pragma unroll
    for (int m = 0; m < 2; ++m) {
        #pragma unroll
        for (int n = 0; n < 2; ++n) {
            int col = w * 32 + n * 16 + lr;
            float bv = bc[col];
            #pragma unroll
            for (int r = 0; r < 4; ++r) {
                int row = m * 16 + kg * 4 + r;
                hcL[row][col] = f2bf(fmaxf(acc[m][n][r] + bv, 0.f));
            }
        }
    }
    __syncthreads();
    int rt = w >> 1, ch = w & 1;
    f32x4 a2[2] = {};
    for (int k0 = 0; k0 < 128; k0 += 32) {
        bf16x8 af = *(const bf16x8*)(&hcL[rt * 16 + lr][k0 + kg * 8]);
        #pragma unroll
        for (int n = 0; n < 2; ++n) {
            int col = ch * 32 + n * 16 + lr;
            bf16x8 bf_ = *(const bf16x8*)(Wto + (size_t)col * 128 + k0 + kg * 8);
            a2[n] = __builtin_amdgcn_mfma_f32_16x16x32_bf16(af, bf_, a2[n], 0, 0, 0);
        }
    }
    #pragma unroll
    for (int n = 0; n < 2; ++n) {
        int col = ch * 32 + n * 16 + lr;
        float bv = bo[col];
        #pragma unroll
        for (int r = 0; r < 4; ++r) {
            int row = r0 + rt * 16 + kg * 4 + r;
            if (row < NN) out[(size_t)row * 64 + col] = a2[n][r] + bv;
        }
    }
}

extern "C" void kernel_launch(void* const* d_in, const int* in_sizes, int n_in,
                              void* d_out, int out_size, void* d_ws, size_t ws_size,
                              hipStream_t stream) {
    const float* x      = (const float*)d_in[0];
    const float* adj    = (const float*)d_in[1];
    const float* W_in   = (const float*)d_in[2];
    const float* b_in   = (const float*)d_in[3];
    const float* W_cheb = (const float*)d_in[4];
    const float* b_cheb = (const float*)d_in[5];
    const float* W_out  = (const float*)d_in[6];
    const float* b_out  = (const float*)d_in[7];
    float* out = (float*)d_out;

    char* ws = (char*)d_ws;
    int*            cnt  = (int*)(ws + 0);                     // 40,000 B
    float*          nrm  = (float*)(ws + 65536);               // 40,000 B
    int*            csr  = (int*)(ws + 131072);                // 5.12 MB
    int*            cnt2 = (int*)(ws + 5308416);               // 5.12 MB [NN][128]
    unsigned short* Xc   = (unsigned short*)(ws + 10485760);   // 7.68 MB
    unsigned short* Wtc  = (unsigned short*)(ws + 18874368);   // 98,304 B
    unsigned short* Wto  = (unsigned short*)(ws + 19005440);   // 16,384 B
    int*            csr2 = (int*)(ws + 20971520);              // 60 MB [NRB][NN][12]

    fat_colscan_gemm<<<FATG, 256, 0, stream>>>(
        adj, csr2, cnt2, x, W_in, b_in, W_cheb, W_out, Xc, Wtc, Wto);
    stitch_norm<<<2500, 256, 0, stream>>>(csr2, cnt2, csr, cnt, nrm);
    prop_k<false><<<(NN + 3) / 4, 256, 0, stream>>>(Xc, csr, cnt, nrm, 0, 128, -1.0f);
    prop_k<true><<<(NN + 3) / 4, 256, 0, stream>>>(Xc, csr, cnt, nrm, 128, 256, -2.0f);
    cheb_out_mfma<<<(NN + 31) / 32, 256, 0, stream>>>(Xc, Wtc, b_cheb, Wto, b_out, out);
}